// Round 8
// baseline (345.593 us; speedup 1.0000x reference)
//
#include <hip/hip_runtime.h>

// GCN layer: out = sum_r segment_sum(vals_r * inp[src_r], dst_r) @ W_r
// Round 8 (5 dispatches, exact low-contention CSR, lookback scan):
//   K1 setup: inp->bf16, W->Wt[r][n][k] bf16, zero counts/state/ticket.
//   K2 hist:  counts[seg]++ for seg=rel*N+dst (400K ctrs, ~2/ctr: no chains).
//   K3 scan:  single-pass decoupled-lookback exclusive scan -> offs[]
//             (ticket-ordered tiles; counts[] preserved).
//   K4 fill:  csr[offs[seg] + countdown(counts[seg])] = {src,val}.
//   K5 fused: block = 32 dst rows. Per relation: gather agg rows from CSR
//             straight into LDS (8 thr/row, f32 regs -> bf16), MFMA with
//             Wt fragments, acc in registers across relations, out f32 once.
// N=50000, R=8, E=100000, IN=OUT=128.

constexpr int IN    = 128;
constexpr int OUT   = 128;
constexpr int BROWS = 32;    // dst rows per fused block
constexpr int LDK   = 136;   // padded LDS row (bf16) = 272 B
constexpr int STILE = 1024;  // scan tile (256 thr x 4)

typedef __attribute__((ext_vector_type(8))) short bf16x8;
typedef __attribute__((ext_vector_type(4))) float f32x4;

__device__ inline unsigned short f2bf(float f) {
    unsigned int u = __float_as_uint(f);
    u += 0x7fffu + ((u >> 16) & 1u);          // RNE
    return (unsigned short)(u >> 16);
}
__device__ inline float bflo(unsigned int u) { return __uint_as_float(u << 16); }
__device__ inline float bfhi(unsigned int u) { return __uint_as_float(u & 0xffff0000u); }

// ---------------- K1: conv inp + conv W + zero counters/state ---------------
__global__ __launch_bounds__(256) void setup_kernel(
    const float* __restrict__ inp, const float* __restrict__ w,
    unsigned short* __restrict__ inpb, unsigned short* __restrict__ wt,
    int* __restrict__ zero_base, int n8, int wt_tot, int nzero)
{
    const int nb_inp = (n8 + 255) / 256;
    const int nb_w   = (wt_tot + 255) / 256;
    const int b = blockIdx.x;
    const int tid = threadIdx.x;
    if (b < nb_inp) {
        const int i = b * 256 + tid;
        if (i < n8) {
            const float4 a = ((const float4*)inp)[i * 2];
            const float4 c = ((const float4*)inp)[i * 2 + 1];
            uint4 o;
            o.x = (unsigned)f2bf(a.x) | ((unsigned)f2bf(a.y) << 16);
            o.y = (unsigned)f2bf(a.z) | ((unsigned)f2bf(a.w) << 16);
            o.z = (unsigned)f2bf(c.x) | ((unsigned)f2bf(c.y) << 16);
            o.w = (unsigned)f2bf(c.z) | ((unsigned)f2bf(c.w) << 16);
            ((uint4*)inpb)[i] = o;
        }
    } else if (b < nb_inp + nb_w) {
        const int t = (b - nb_inp) * 256 + tid;
        if (t < wt_tot) {
            const int r = t >> 14, rem = t & 16383;
            const int n = rem >> 7, k = rem & 127;
            wt[t] = f2bf(w[(r << 14) + (k << 7) + n]);   // Wt[r][n][k]
        }
    } else {
        const int i = (b - nb_inp - nb_w) * 256 + tid;
        if (i < nzero) zero_base[i] = 0;
    }
}

// ---------------- K2: histogram over seg = rel*N + dst ----------------------
__global__ __launch_bounds__(256) void hist_kernel(
    const int* __restrict__ dst, int* __restrict__ counts,
    int n_edges, int n_nodes)
{
    const int e = blockIdx.x * 256 + threadIdx.x;
    if (e >= n_edges) return;
    const size_t g = (size_t)blockIdx.y * n_edges + e;
    atomicAdd(&counts[blockIdx.y * n_nodes + dst[g]], 1);
}

// ---------------- K3: single-pass exclusive scan (decoupled lookback) -------
// state[tile] = (flag<<32)|sum, flag 1=aggregate 2=inclusive-prefix.
// Ticket ordering => tile t's predecessors are already executing => their
// aggregates appear without waiting on anyone => lookback terminates.
__global__ __launch_bounds__(256) void scan_kernel(
    const int* __restrict__ counts, int* __restrict__ offs,
    unsigned long long* __restrict__ state, int* __restrict__ ticket, int S)
{
    __shared__ int ps[256];
    __shared__ int tile_s;
    __shared__ int base_s;
    const int tid = threadIdx.x;
    if (tid == 0) tile_s = atomicAdd(ticket, 1);
    __syncthreads();
    const int tile = tile_s;
    const int base = tile * STILE + tid * 4;

    int c[4];
    #pragma unroll
    for (int i = 0; i < 4; ++i) c[i] = (base + i < S) ? counts[base + i] : 0;
    const int mysum = c[0] + c[1] + c[2] + c[3];
    ps[tid] = mysum;
    __syncthreads();
    #pragma unroll
    for (int d = 1; d < 256; d <<= 1) {
        const int v = (tid >= d) ? ps[tid - d] : 0;
        __syncthreads();
        ps[tid] += v;
        __syncthreads();
    }
    const int block_total = ps[255];

    if (tid == 0) {
        if (tile == 0) {
            __hip_atomic_store(&state[0],
                (2ull << 32) | (unsigned long long)(unsigned)block_total,
                __ATOMIC_RELEASE, __HIP_MEMORY_SCOPE_AGENT);
            base_s = 0;
        } else {
            __hip_atomic_store(&state[tile],
                (1ull << 32) | (unsigned long long)(unsigned)block_total,
                __ATOMIC_RELEASE, __HIP_MEMORY_SCOPE_AGENT);
            long long run = 0;
            int t = tile - 1;
            for (;;) {
                const unsigned long long st = __hip_atomic_load(
                    &state[t], __ATOMIC_ACQUIRE, __HIP_MEMORY_SCOPE_AGENT);
                const unsigned flag = (unsigned)(st >> 32);
                if (flag == 0) { __builtin_amdgcn_s_sleep(1); continue; }
                run += (long long)(unsigned)st;
                if (flag == 2u) break;
                --t;
            }
            base_s = (int)run;
            __hip_atomic_store(&state[tile],
                (2ull << 32) | (unsigned long long)(unsigned)(run + block_total),
                __ATOMIC_RELEASE, __HIP_MEMORY_SCOPE_AGENT);
        }
    }
    __syncthreads();
    int excl = base_s + ps[tid] - mysum;
    #pragma unroll
    for (int i = 0; i < 4; ++i) {
        if (base + i < S) offs[base + i] = excl;
        excl += c[i];
    }
}

// ---------------- K4: fill (countdown allocation; counts -> 0) --------------
__global__ __launch_bounds__(256) void fill_kernel(
    const int* __restrict__ src, const int* __restrict__ dst,
    const float* __restrict__ vals, int* __restrict__ counts,
    const int* __restrict__ offs, int2* __restrict__ csr,
    int n_edges, int n_nodes)
{
    const int e = blockIdx.x * 256 + threadIdx.x;
    if (e >= n_edges) return;
    const size_t g = (size_t)blockIdx.y * n_edges + e;
    const int seg = blockIdx.y * n_nodes + dst[g];
    const int idx = atomicAdd(&counts[seg], -1) - 1;   // c-1 .. 0
    csr[offs[seg] + idx] = make_int2(src[g], __float_as_int(vals[g]));
}

// ---------------- K5: fused aggregate + GEMM --------------------------------
// Block: 32 dst rows x 128 cols, 256 thr = 4 waves. Per relation: thread
// (row=t>>3, oct=t&7) gathers sum val*inpb[src][oct*16..+15] over the CSR
// run of seg=(r*N+row) into 16 f32 regs, packs bf16 into As; then 16 MFMAs
// (2 M-tiles x 2 N-tiles x K=128 per wave); acc persists across relations.
__global__ __launch_bounds__(256) void fused_kernel(
    const unsigned short* __restrict__ inpb,
    const unsigned short* __restrict__ wt,
    const int2* __restrict__ csr, const int* __restrict__ offs,
    float* __restrict__ out, int n_nodes, int n_rel, int total_edges)
{
    __shared__ unsigned short As[BROWS * LDK];   // 8.7 KB

    const int row0 = blockIdx.x * BROWS;
    const int tid  = threadIdx.x;
    const int wave = tid >> 6, lane = tid & 63;
    const int m = lane & 15, q = lane >> 4;
    const int srow = tid >> 3, oct = tid & 7;

    const int S = n_rel * n_nodes;

    f32x4 acc[2][2];
    #pragma unroll
    for (int mt = 0; mt < 2; ++mt)
        #pragma unroll
        for (int nt = 0; nt < 2; ++nt)
            acc[mt][nt] = (f32x4){0.f, 0.f, 0.f, 0.f};

    for (int r = 0; r < n_rel; ++r) {
        __syncthreads();   // As reuse across relations

        // ---- stage: agg row for (r, row0+srow), cols oct*16..+15 ----
        float accs[16];
        #pragma unroll
        for (int i = 0; i < 16; ++i) accs[i] = 0.f;
        const int grow = row0 + srow;
        if (grow < n_nodes) {
            const int seg = r * n_nodes + grow;
            const int b = offs[seg];
            const int e = (seg + 1 < S) ? offs[seg + 1] : total_edges;
            for (int j = b; j < e; ++j) {
                const int2 rec = csr[j];
                const float v = __int_as_float(rec.y);
                const uint4* gp = (const uint4*)(
                    inpb + (size_t)rec.x * IN + oct * 16);
                const uint4 u0 = gp[0], u1 = gp[1];
                accs[0]  += v * bflo(u0.x);  accs[1]  += v * bfhi(u0.x);
                accs[2]  += v * bflo(u0.y);  accs[3]  += v * bfhi(u0.y);
                accs[4]  += v * bflo(u0.z);  accs[5]  += v * bfhi(u0.z);
                accs[6]  += v * bflo(u0.w);  accs[7]  += v * bfhi(u0.w);
                accs[8]  += v * bflo(u1.x);  accs[9]  += v * bfhi(u1.x);
                accs[10] += v * bflo(u1.y);  accs[11] += v * bfhi(u1.y);
                accs[12] += v * bflo(u1.z);  accs[13] += v * bfhi(u1.z);
                accs[14] += v * bflo(u1.w);  accs[15] += v * bfhi(u1.w);
            }
        }
        {
            unsigned int* lp = (unsigned int*)&As[srow * LDK + oct * 16];
            #pragma unroll
            for (int i = 0; i < 8; ++i)
                lp[i] = (unsigned)f2bf(accs[2 * i])
                      | ((unsigned)f2bf(accs[2 * i + 1]) << 16);
        }

        // ---- B fragments for this relation (L2-hot wt) ----
        bf16x8 bfrag[2][4];
        {
            const unsigned short* wtr = wt + ((size_t)r * OUT + wave * 32) * IN;
            #pragma unroll
            for (int nt = 0; nt < 2; ++nt)
                #pragma unroll
                for (int ks = 0; ks < 4; ++ks)
                    bfrag[nt][ks] = *(const bf16x8*)(
                        wtr + (size_t)(nt * 16 + m) * IN + ks * 32 + q * 8);
        }
        __syncthreads();

        // ---- MFMA: 2 M-tiles x 2 N-tiles, K=128 ----
        #pragma unroll
        for (int ks = 0; ks < 4; ++ks) {
            bf16x8 a[2];
            #pragma unroll
            for (int mt = 0; mt < 2; ++mt)
                a[mt] = *(const bf16x8*)&As[(mt * 16 + m) * LDK + ks * 32 + q * 8];
            #pragma unroll
            for (int mt = 0; mt < 2; ++mt) {
                acc[mt][0] = __builtin_amdgcn_mfma_f32_16x16x32_bf16(
                    a[mt], bfrag[0][ks], acc[mt][0], 0, 0, 0);
                acc[mt][1] = __builtin_amdgcn_mfma_f32_16x16x32_bf16(
                    a[mt], bfrag[1][ks], acc[mt][1], 0, 0, 0);
            }
        }
    }

    // ---- store: C/D lane holds rows q*4+0..3, col = nt*16 + m ----
    #pragma unroll
    for (int mt = 0; mt < 2; ++mt) {
        #pragma unroll
        for (int rg = 0; rg < 4; ++rg) {
            const int row = row0 + mt * 16 + q * 4 + rg;
            if (row < n_nodes) {
                float* op = out + (size_t)row * OUT + wave * 32 + m;
                op[0]  = acc[mt][0][rg];
                op[16] = acc[mt][1][rg];
            }
        }
    }
}

// ---------------- last resort: per-edge GEMV scatter (no workspace) ---------
__global__ __launch_bounds__(256) void gemv_scatter_kernel(
    const float* __restrict__ inp, const float* __restrict__ weights,
    const int* __restrict__ src, const int* __restrict__ dst,
    const float* __restrict__ vals, float* __restrict__ out, int n_edges)
{
    const int e = blockIdx.x * 4 + (threadIdx.x >> 6);
    if (e >= n_edges) return;
    const int lane = threadIdx.x & 63;
    const int r = blockIdx.y;
    const size_t g = (size_t)r * n_edges + e;
    const int s = src[g], d = dst[g];
    const float v = vals[g];
    const float* __restrict__ arow = inp + (size_t)s * IN;
    const float* __restrict__ W = weights + (size_t)r * IN * OUT;
    float a0 = 0.f, a1 = 0.f;
    for (int k = 0; k < IN; ++k) {
        const float av = arow[k];
        a0 = fmaf(av, W[k * OUT + lane], a0);
        a1 = fmaf(av, W[k * OUT + lane + 64], a1);
    }
    float* orow = out + (size_t)d * OUT;
    __hip_atomic_fetch_add(orow + lane, v * a0, __ATOMIC_RELAXED,
                           __HIP_MEMORY_SCOPE_AGENT);
    __hip_atomic_fetch_add(orow + lane + 64, v * a1, __ATOMIC_RELAXED,
                           __HIP_MEMORY_SCOPE_AGENT);
}

extern "C" void kernel_launch(void* const* d_in, const int* in_sizes, int n_in,
                              void* d_out, int out_size, void* d_ws, size_t ws_size,
                              hipStream_t stream) {
    const float* inp     = (const float*)d_in[0];
    const int*   src     = (const int*)  d_in[1];
    const int*   dst     = (const int*)  d_in[2];
    const float* vals    = (const float*)d_in[3];
    const float* weights = (const float*)d_in[4];
    float* out = (float*)d_out;

    const int n_nodes = in_sizes[0] / IN;            // 50000
    const int n_rel   = in_sizes[4] / (IN * OUT);    // 8
    const int n_edges = in_sizes[1] / n_rel;         // 100000
    const int total_edges = n_rel * n_edges;
    const int S = n_rel * n_nodes;                   // 400K segments
    const int nb_scan = (S + STILE - 1) / STILE;     // 391 tiles

    auto align_up = [](size_t x) { return (x + 255) & ~(size_t)255; };
    const size_t sz_inpb  = align_up((size_t)n_nodes * IN * 2);
    const size_t sz_wt    = align_up((size_t)n_rel * IN * OUT * 2);
    // zero region: counts[S] + state[nb_scan] (u64) + ticket[1], contiguous
    const size_t sz_zero  = align_up((size_t)S * 4 + (size_t)nb_scan * 8 + 8);
    const size_t sz_offs  = align_up((size_t)S * 4);
    const size_t sz_csr   = align_up((size_t)total_edges * 8);
    const size_t need = sz_inpb + sz_wt + sz_zero + sz_offs + sz_csr;

    const int n8 = n_nodes * IN / 8;
    const int wt_tot = n_rel * IN * OUT;

    if (need <= ws_size) {
        char* p = (char*)d_ws;
        unsigned short* inpb = (unsigned short*)p;  p += sz_inpb;
        unsigned short* wtb  = (unsigned short*)p;  p += sz_wt;
        int* counts = (int*)p;
        unsigned long long* state = (unsigned long long*)(p + (size_t)S * 4);
        int* ticket = (int*)(p + (size_t)S * 4 + (size_t)nb_scan * 8);
        p += sz_zero;
        int*  offs = (int*)p;   p += sz_offs;
        int2* csr  = (int2*)p;

        const int nzero = S + nb_scan * 2 + 2;   // ints to zero
        const int nb_inp = (n8 + 255) / 256;
        const int nb_w   = (wt_tot + 255) / 256;
        const int nb_z   = (nzero + 255) / 256;
        setup_kernel<<<nb_inp + nb_w + nb_z, 256, 0, stream>>>(
            inp, weights, inpb, wtb, counts, n8, wt_tot, nzero);

        dim3 eg((n_edges + 255) / 256, n_rel);
        hist_kernel<<<eg, 256, 0, stream>>>(dst, counts, n_edges, n_nodes);

        scan_kernel<<<nb_scan, 256, 0, stream>>>(counts, offs, state, ticket, S);

        fill_kernel<<<eg, 256, 0, stream>>>(src, dst, vals, counts, offs, csr,
                                            n_edges, n_nodes);

        const int fuse_gx = (n_nodes + BROWS - 1) / BROWS;
        fused_kernel<<<fuse_gx, 256, 0, stream>>>(
            inpb, wtb, csr, offs, out, n_nodes, n_rel, total_edges);
        return;
    }

    // last resort: no workspace needed
    hipMemsetAsync(out, 0, (size_t)n_nodes * OUT * 4, stream);
    dim3 g((n_edges + 3) / 4, n_rel);
    gemv_scatter_kernel<<<g, 256, 0, stream>>>(inp, weights, src, dst, vals,
                                               out, n_edges);
}